// Round 1
// baseline (346.068 us; speedup 1.0000x reference)
//
#include <hip/hip_runtime.h>
#include <math.h>

static constexpr int H = 512;
static constexpr int B = 64;

// =====================================================================
// Generic tiled fp32 GEMM: C[64][N] (+bias) = A[64][K] * op(W)
//   WNK=true : W is [N][K] row-major  -> C = A · Wᵀ   (torch Linear)
//   WNK=false: W is [K][N] row-major  -> C = A · W
// 64x64 output tile per block, 256 threads, 4x4 micro-tile per thread.
// LDS tiles stored K-major ([kk][row]) with pad 68 (16B-aligned rows).
// =====================================================================
template<bool WNK>
__global__ __launch_bounds__(256) void gemm_a64(
    const float* __restrict__ A, const float* __restrict__ W,
    const float* __restrict__ bias, float* __restrict__ C,
    int K, int N, int ldc)
{
    __shared__ float As[64][68];
    __shared__ float Bs[64][68];
    const int tid = threadIdx.x;
    const int n0 = blockIdx.x * 64;
    const int tv = tid & 15;   // v-group (4 cols each)
    const int tb = tid >> 4;   // b-group (4 rows each)

    const int lrow = tid >> 2;         // 0..63, loader row
    const int lk0  = (tid & 3) * 16;   // loader k-segment base

    float acc[4][4] = {{0.f, 0.f, 0.f, 0.f}};

    for (int kc = 0; kc < K; kc += 64) {
        // ---- stage A[0:64][kc:kc+64] -> As[k][b] (transposed) ----
        #pragma unroll
        for (int i = 0; i < 4; ++i) {
            const float4 a = *(const float4*)(A + (size_t)lrow * K + kc + lk0 + 4 * i);
            As[lk0 + 4 * i + 0][lrow] = a.x;
            As[lk0 + 4 * i + 1][lrow] = a.y;
            As[lk0 + 4 * i + 2][lrow] = a.z;
            As[lk0 + 4 * i + 3][lrow] = a.w;
        }
        // ---- stage W tile -> Bs[k][v] ----
        if (WNK) {
            int wr = n0 + lrow;
            if (wr > N - 1) wr = N - 1;   // clamp (writes guarded later)
            #pragma unroll
            for (int i = 0; i < 4; ++i) {
                const float4 w = *(const float4*)(W + (size_t)wr * K + kc + lk0 + 4 * i);
                Bs[lk0 + 4 * i + 0][lrow] = w.x;
                Bs[lk0 + 4 * i + 1][lrow] = w.y;
                Bs[lk0 + 4 * i + 2][lrow] = w.z;
                Bs[lk0 + 4 * i + 3][lrow] = w.w;
            }
        } else {
            const int v  = tid & 63;
            const int kg = tid >> 6;   // 0..3
            #pragma unroll
            for (int i = 0; i < 16; ++i) {
                const int kk = kg * 16 + i;
                Bs[kk][v] = (n0 + v < N) ? W[(size_t)(kc + kk) * N + n0 + v] : 0.f;
            }
        }
        __syncthreads();

        #pragma unroll 16
        for (int kk = 0; kk < 64; ++kk) {
            const float4 a = *(const float4*)&As[kk][tb * 4];
            const float4 b = *(const float4*)&Bs[kk][tv * 4];
            acc[0][0] += a.x * b.x; acc[0][1] += a.x * b.y; acc[0][2] += a.x * b.z; acc[0][3] += a.x * b.w;
            acc[1][0] += a.y * b.x; acc[1][1] += a.y * b.y; acc[1][2] += a.y * b.z; acc[1][3] += a.y * b.w;
            acc[2][0] += a.z * b.x; acc[2][1] += a.z * b.y; acc[2][2] += a.z * b.z; acc[2][3] += a.z * b.w;
            acc[3][0] += a.w * b.x; acc[3][1] += a.w * b.y; acc[3][2] += a.w * b.z; acc[3][3] += a.w * b.w;
        }
        __syncthreads();
    }

    #pragma unroll
    for (int i = 0; i < 4; ++i) {
        const int bb = tb * 4 + i;
        #pragma unroll
        for (int j = 0; j < 4; ++j) {
            const int n = n0 + tv * 4 + j;
            if (n < N) C[(size_t)bb * ldc + n] = acc[i][j] + (bias ? bias[n] : 0.f);
        }
    }
}

// =====================================================================
// GRU gates (PyTorch order r,z,n): h' = (1-z)*n + z*h
// one block per b, one thread per h
// =====================================================================
__global__ __launch_bounds__(512) void gru_gates(
    const float* __restrict__ gi, const float* __restrict__ gh,
    const float* __restrict__ h0, float* __restrict__ hnew,
    float* __restrict__ combined)
{
    const int b = blockIdx.x;
    const int h = threadIdx.x;
    const size_t o = (size_t)b * 3 * H;
    const float gir = gi[o + h];
    const float giz = gi[o + H + h];
    const float gin = gi[o + 2 * H + h];
    const float ghr = gh[o + h];
    const float ghz = gh[o + H + h];
    const float ghn = gh[o + 2 * H + h];
    const float r = 1.f / (1.f + expf(-(gir + ghr)));
    const float z = 1.f / (1.f + expf(-(giz + ghz)));
    const float n = tanhf(gin + r * ghn);
    const float hp = h0[(size_t)b * H + h];
    const float hn = (1.f - z) * n + z * hp;
    hnew[(size_t)b * H + h] = hn;
    combined[(size_t)b * 2 * H + h] = hn;
}

// =====================================================================
// energy[s][b] = dot(tmp[b,:], enc[s,b,:]) + bilin_b   (one wave per (s,b))
// =====================================================================
__global__ __launch_bounds__(256) void energy_k(
    const float* __restrict__ tmp, const float* __restrict__ enc,
    const float* __restrict__ bilin_b, float* __restrict__ energy, int S)
{
    const int gw = (int)((blockIdx.x * 256 + threadIdx.x) >> 6);
    const int lane = threadIdx.x & 63;
    if (gw >= S * B) return;
    const int s = gw >> 6;
    const int b = gw & 63;
    const float* e = enc + ((size_t)s * B + b) * H;
    const float* t = tmp + (size_t)b * H;
    const int k0 = lane * 8;   // H = 512 = 64 lanes * 8
    const float4 e0 = *(const float4*)(e + k0);
    const float4 e1 = *(const float4*)(e + k0 + 4);
    const float4 t0 = *(const float4*)(t + k0);
    const float4 t1 = *(const float4*)(t + k0 + 4);
    float p = e0.x * t0.x + e0.y * t0.y + e0.z * t0.z + e0.w * t0.w
            + e1.x * t1.x + e1.y * t1.y + e1.z * t1.z + e1.w * t1.w;
    #pragma unroll
    for (int off = 32; off; off >>= 1) p += __shfl_down(p, off);
    if (lane == 0) energy[(size_t)s * B + b] = p + bilin_b[0];
}

// =====================================================================
// softmax over s (axis 0) for each column b; writes attn [S][B]
// =====================================================================
__global__ __launch_bounds__(128) void softmax_s(
    const float* __restrict__ energy, float* __restrict__ attn, int S)
{
    const int b = blockIdx.x;
    const int t = threadIdx.x;
    __shared__ float w0[2], w1[2];
    float m = -1e30f;
    for (int s = t; s < S; s += 128) m = fmaxf(m, energy[(size_t)s * B + b]);
    #pragma unroll
    for (int off = 32; off; off >>= 1) m = fmaxf(m, __shfl_xor(m, off));
    if ((t & 63) == 0) w0[t >> 6] = m;
    __syncthreads();
    m = fmaxf(w0[0], w0[1]);
    float sum = 0.f;
    for (int s = t; s < S; s += 128) sum += expf(energy[(size_t)s * B + b] - m);
    #pragma unroll
    for (int off = 32; off; off >>= 1) sum += __shfl_xor(sum, off);
    if ((t & 63) == 0) w1[t >> 6] = sum;
    __syncthreads();
    const float inv = 1.f / (w1[0] + w1[1]);
    for (int s = t; s < S; s += 128)
        attn[(size_t)s * B + b] = expf(energy[(size_t)s * B + b] - m) * inv;
}

// =====================================================================
// context[b][h] = sum_s attn[s][b] * enc[s][b][h]  -> combined[b][H+h]
// one block per b, one thread per h; attn column staged in LDS
// =====================================================================
__global__ __launch_bounds__(512) void context_k(
    const float* __restrict__ attn, const float* __restrict__ enc,
    float* __restrict__ combined, int S)
{
    const int b = blockIdx.x;
    const int h = threadIdx.x;
    __shared__ float a_s[1024];
    for (int s = h; s < S; s += 512) a_s[s] = attn[(size_t)s * B + b];
    __syncthreads();
    float c = 0.f;
    const float* e = enc + (size_t)b * H + h;
    #pragma unroll 4
    for (int s = 0; s < S; ++s) c += a_s[s] * e[(size_t)s * B * H];
    combined[(size_t)b * 2 * H + H + h] = c;
}

// =====================================================================
// in-place log_softmax over each row of logits [B][V]
// =====================================================================
__global__ __launch_bounds__(1024) void logsoftmax_k(float* __restrict__ logits, int V)
{
    const int b = blockIdx.x;
    const int t = threadIdx.x;
    float* row = logits + (size_t)b * V;
    __shared__ float wm[16], ws_[16];

    float m = -1e30f;
    for (int v = t; v < V; v += 1024) m = fmaxf(m, row[v]);
    #pragma unroll
    for (int off = 32; off; off >>= 1) m = fmaxf(m, __shfl_xor(m, off));
    if ((t & 63) == 0) wm[t >> 6] = m;
    __syncthreads();
    m = wm[0];
    #pragma unroll
    for (int i = 1; i < 16; ++i) m = fmaxf(m, wm[i]);

    float s = 0.f;
    for (int v = t; v < V; v += 1024) s += expf(row[v] - m);
    #pragma unroll
    for (int off = 32; off; off >>= 1) s += __shfl_xor(s, off);
    if ((t & 63) == 0) ws_[t >> 6] = s;
    __syncthreads();
    s = 0.f;
    #pragma unroll
    for (int i = 0; i < 16; ++i) s += ws_[i];

    const float c = m + logf(s);
    for (int v = t; v < V; v += 1024) row[v] = row[v] - c;
}

// =====================================================================
extern "C" void kernel_launch(void* const* d_in, const int* in_sizes, int n_in,
                              void* d_out, int out_size, void* d_ws, size_t ws_size,
                              hipStream_t stream)
{
    const float* embedded = (const float*)d_in[0];   // [B][E]  E=512
    const float* hidden   = (const float*)d_in[1];   // [1][B][H]
    const float* enc      = (const float*)d_in[2];   // [S][B][H]
    const float* w_ih     = (const float*)d_in[3];   // [3H][E]
    const float* w_hh     = (const float*)d_in[4];   // [3H][H]
    const float* b_ih     = (const float*)d_in[5];
    const float* b_hh     = (const float*)d_in[6];
    const float* bilin_w  = (const float*)d_in[7];   // [1][H][H]
    const float* bilin_b  = (const float*)d_in[8];   // [1]
    const float* out_w    = (const float*)d_in[9];   // [V][2H]
    const float* out_b    = (const float*)d_in[10];  // [V]
    float* out = (float*)d_out;

    const int E = in_sizes[0] / B;            // 512
    const int S = in_sizes[2] / (B * H);      // 400
    const int V = in_sizes[9] / (2 * H);      // 50000

    // d_out layout: logp [B][V], h_new [B][H], attn [S][B]
    float* logp = out;
    float* hnew = out + (size_t)B * V;
    float* attn = hnew + (size_t)B * H;

    // workspace layout (floats)
    float* ws       = (float*)d_ws;
    float* gi       = ws;                      // B*3H
    float* gh       = gi + (size_t)B * 3 * H;  // B*3H
    float* tmp      = gh + (size_t)B * 3 * H;  // B*H
    float* energy   = tmp + (size_t)B * H;     // S*B
    float* combined = energy + (size_t)S * B;  // B*2H

    // 1) gi = embedded @ w_ih.T + b_ih ; gh = h0 @ w_hh.T + b_hh
    gemm_a64<true><<<(3 * H) / 64, 256, 0, stream>>>(embedded, w_ih, b_ih, gi, E, 3 * H, 3 * H);
    gemm_a64<true><<<(3 * H) / 64, 256, 0, stream>>>(hidden, w_hh, b_hh, gh, H, 3 * H, 3 * H);

    // 2) GRU gates -> h_new (d_out) and combined[:, :H]
    gru_gates<<<B, H, 0, stream>>>(gi, gh, hidden, hnew, combined);

    // 3) tmp = h_new @ bilin_w[0]   (W is [K][N] layout)
    gemm_a64<false><<<H / 64, 256, 0, stream>>>(hnew, bilin_w, nullptr, tmp, H, H, H);

    // 4) energy[s][b] = tmp[b] . enc[s,b] + bilin_b
    energy_k<<<(S * B + 3) / 4, 256, 0, stream>>>(tmp, enc, bilin_b, energy, S);

    // 5) attn = softmax_s(energy)  -> d_out attn segment
    softmax_s<<<B, 128, 0, stream>>>(energy, attn, S);

    // 6) context -> combined[:, H:]
    context_k<<<B, H, 0, stream>>>(attn, enc, combined, S);

    // 7) logits = combined @ out_w.T + out_b  -> d_out logp segment
    gemm_a64<true><<<(V + 63) / 64, 256, 0, stream>>>(combined, out_w, out_b, logp, 2 * H, V, V);

    // 8) in-place log_softmax
    logsoftmax_k<<<B, 1024, 0, stream>>>(logp, V);
}

// Round 2
// 178.901 us; speedup vs baseline: 1.9344x; 1.9344x over previous
//
#include <hip/hip_runtime.h>
#include <math.h>

static constexpr int H = 512;
static constexpr int B = 64;

typedef __bf16 bf16x8 __attribute__((ext_vector_type(8)));
typedef __bf16 bf16x4 __attribute__((ext_vector_type(4)));
typedef float f32x4 __attribute__((ext_vector_type(4)));

// =====================================================================
// bf16-MFMA GEMM: C[64][N] = A[64][K](fp32) @ W[N][K](fp32)^T + bias
// fp32 -> bf16 in-register conversion while staging into swizzled LDS.
// Tile 64M x 64N x 64K. 256 thr / 4 waves; wave w -> N cols [w*16, w*16+16),
// 4 M-frags of 16. Double-buffered LDS, 1 barrier per K-step, prefetch
// issued between barrier and MFMA.
// LDS layout: row-major [64][64] bf16, elem offset ^= (row&7)<<3 (16B swizzle).
// =====================================================================
__global__ __launch_bounds__(256) void gemm_mfma_nt(
    const float* __restrict__ A,   // [64][K]
    const float* __restrict__ W,   // [N][K]
    const float* __restrict__ bias,
    float* __restrict__ C,         // [64][ldc]
    int K, int N, int ldc)
{
    __shared__ __bf16 As[2][64 * 64];
    __shared__ __bf16 Ws[2][64 * 64];

    const int tid  = threadIdx.x;
    const int lane = tid & 63;
    const int wv   = tid >> 6;            // wave 0..3
    const int n0   = blockIdx.x * 64;

    const int lrow = tid >> 2;            // 0..63 staging row
    const int lq   = tid & 3;             // 0..3  staging quarter (16 floats)

    int wrow = n0 + lrow;
    if (wrow > N - 1) wrow = N - 1;       // clamp; invalid cols never stored
    const float* Aptr = A + (size_t)lrow * K + lq * 16;
    const float* Wptr = W + (size_t)wrow * K + lq * 16;

    f32x4 acc[4] = {};

    float4 ra[4], rw[4];
    #pragma unroll
    for (int i = 0; i < 4; ++i) {
        ra[i] = *(const float4*)(Aptr + 4 * i);
        rw[i] = *(const float4*)(Wptr + 4 * i);
    }

    const int ln = lane & 15;
    const int lk = (lane >> 4) << 3;      // 0,8,16,24 (k-chunk base)
    const int NT = K >> 6;

    for (int t = 0; t < NT; ++t) {
        __bf16* a_s = As[t & 1];
        __bf16* w_s = Ws[t & 1];
        // ---- convert + swizzled LDS write ----
        #pragma unroll
        for (int i = 0; i < 4; ++i) {
            const int off = ((lrow << 6) + lq * 16 + 4 * i) ^ ((lrow & 7) << 3);
            bf16x4 va = { (__bf16)ra[i].x, (__bf16)ra[i].y, (__bf16)ra[i].z, (__bf16)ra[i].w };
            bf16x4 vw = { (__bf16)rw[i].x, (__bf16)rw[i].y, (__bf16)rw[i].z, (__bf16)rw[i].w };
            *(bf16x4*)&a_s[off] = va;
            *(bf16x4*)&w_s[off] = vw;
        }
        __syncthreads();
        // ---- prefetch next K-tile (overlaps MFMA below) ----
        if (t + 1 < NT) {
            const float* Ap = Aptr + (t + 1) * 64;
            const float* Wp = Wptr + (t + 1) * 64;
            #pragma unroll
            for (int i = 0; i < 4; ++i) {
                ra[i] = *(const float4*)(Ap + 4 * i);
                rw[i] = *(const float4*)(Wp + 4 * i);
            }
        }
        // ---- MFMA on current tile ----
        bf16x8 bfrag[2];
        #pragma unroll
        for (int ks = 0; ks < 2; ++ks) {
            const int row = wv * 16 + ln;
            const int off = ((row << 6) + ks * 32 + lk) ^ ((row & 7) << 3);
            bfrag[ks] = *(bf16x8*)&w_s[off];
        }
        #pragma unroll
        for (int m = 0; m < 4; ++m) {
            const int row = m * 16 + ln;
            #pragma unroll
            for (int ks = 0; ks < 2; ++ks) {
                const int off = ((row << 6) + ks * 32 + lk) ^ ((row & 7) << 3);
                bf16x8 afrag = *(bf16x8*)&a_s[off];
                acc[m] = __builtin_amdgcn_mfma_f32_16x16x32_bf16(afrag, bfrag[ks], acc[m], 0, 0, 0);
            }
        }
        // no trailing barrier needed: next iter writes the other buffer;
        // writes to THIS buffer are 2 iters away, past the next barrier.
    }

    // ---- epilogue: C row(M) = (lane>>4)*4 + j, col(N) = lane&15 ----
    const int col = n0 + wv * 16 + ln;
    if (col < N) {
        const float bv = bias ? bias[col] : 0.f;
        #pragma unroll
        for (int m = 0; m < 4; ++m) {
            const int rbase = m * 16 + (lane >> 4) * 4;
            #pragma unroll
            for (int j = 0; j < 4; ++j)
                C[(size_t)(rbase + j) * ldc + col] = acc[m][j] + bv;
        }
    }
}

// =====================================================================
// fp32 tiled GEMM, W in [K][N] layout (kept for the tiny bilinear GEMM)
// =====================================================================
__global__ __launch_bounds__(256) void gemm_a64_kn(
    const float* __restrict__ A, const float* __restrict__ W,
    float* __restrict__ C, int K, int N, int ldc)
{
    __shared__ float As[64][68];
    __shared__ float Bs[64][68];
    const int tid = threadIdx.x;
    const int n0 = blockIdx.x * 64;
    const int tv = tid & 15;
    const int tb = tid >> 4;
    const int lrow = tid >> 2;
    const int lk0  = (tid & 3) * 16;

    float acc[4][4] = {{0.f, 0.f, 0.f, 0.f}};

    for (int kc = 0; kc < K; kc += 64) {
        #pragma unroll
        for (int i = 0; i < 4; ++i) {
            const float4 a = *(const float4*)(A + (size_t)lrow * K + kc + lk0 + 4 * i);
            As[lk0 + 4 * i + 0][lrow] = a.x;
            As[lk0 + 4 * i + 1][lrow] = a.y;
            As[lk0 + 4 * i + 2][lrow] = a.z;
            As[lk0 + 4 * i + 3][lrow] = a.w;
        }
        {
            const int v  = tid & 63;
            const int kg = tid >> 6;
            #pragma unroll
            for (int i = 0; i < 16; ++i) {
                const int kk = kg * 16 + i;
                Bs[kk][v] = (n0 + v < N) ? W[(size_t)(kc + kk) * N + n0 + v] : 0.f;
            }
        }
        __syncthreads();
        #pragma unroll 16
        for (int kk = 0; kk < 64; ++kk) {
            const float4 a = *(const float4*)&As[kk][tb * 4];
            const float4 b = *(const float4*)&Bs[kk][tv * 4];
            acc[0][0] += a.x * b.x; acc[0][1] += a.x * b.y; acc[0][2] += a.x * b.z; acc[0][3] += a.x * b.w;
            acc[1][0] += a.y * b.x; acc[1][1] += a.y * b.y; acc[1][2] += a.y * b.z; acc[1][3] += a.y * b.w;
            acc[2][0] += a.z * b.x; acc[2][1] += a.z * b.y; acc[2][2] += a.z * b.z; acc[2][3] += a.z * b.w;
            acc[3][0] += a.w * b.x; acc[3][1] += a.w * b.y; acc[3][2] += a.w * b.z; acc[3][3] += a.w * b.w;
        }
        __syncthreads();
    }
    #pragma unroll
    for (int i = 0; i < 4; ++i) {
        const int bb = tb * 4 + i;
        #pragma unroll
        for (int j = 0; j < 4; ++j) {
            const int n = n0 + tv * 4 + j;
            if (n < N) C[(size_t)bb * ldc + n] = acc[i][j];
        }
    }
}

// =====================================================================
// GRU gates (r,z,n): h' = (1-z)*n + z*h
// =====================================================================
__global__ __launch_bounds__(512) void gru_gates(
    const float* __restrict__ gi, const float* __restrict__ gh,
    const float* __restrict__ h0, float* __restrict__ hnew,
    float* __restrict__ combined)
{
    const int b = blockIdx.x;
    const int h = threadIdx.x;
    const size_t o = (size_t)b * 3 * H;
    const float r = 1.f / (1.f + expf(-(gi[o + h] + gh[o + h])));
    const float z = 1.f / (1.f + expf(-(gi[o + H + h] + gh[o + H + h])));
    const float n = tanhf(gi[o + 2 * H + h] + r * gh[o + 2 * H + h]);
    const float hn = (1.f - z) * n + z * h0[(size_t)b * H + h];
    hnew[(size_t)b * H + h] = hn;
    combined[(size_t)b * 2 * H + h] = hn;
}

// =====================================================================
// energy[s][b] = dot(tmp[b,:], enc[s,b,:]) + bilin_b   (one wave per (s,b))
// =====================================================================
__global__ __launch_bounds__(256) void energy_k(
    const float* __restrict__ tmp, const float* __restrict__ enc,
    const float* __restrict__ bilin_b, float* __restrict__ energy, int S)
{
    const int gw = (int)((blockIdx.x * 256 + threadIdx.x) >> 6);
    const int lane = threadIdx.x & 63;
    if (gw >= S * B) return;
    const int s = gw >> 6;
    const int b = gw & 63;
    const float* e = enc + ((size_t)s * B + b) * H;
    const float* t = tmp + (size_t)b * H;
    const int k0 = lane * 8;
    const float4 e0 = *(const float4*)(e + k0);
    const float4 e1 = *(const float4*)(e + k0 + 4);
    const float4 t0 = *(const float4*)(t + k0);
    const float4 t1 = *(const float4*)(t + k0 + 4);
    float p = e0.x * t0.x + e0.y * t0.y + e0.z * t0.z + e0.w * t0.w
            + e1.x * t1.x + e1.y * t1.y + e1.z * t1.z + e1.w * t1.w;
    #pragma unroll
    for (int off = 32; off; off >>= 1) p += __shfl_down(p, off);
    if (lane == 0) energy[(size_t)s * B + b] = p + bilin_b[0];
}

// =====================================================================
// softmax over s for each column b
// =====================================================================
__global__ __launch_bounds__(128) void softmax_s(
    const float* __restrict__ energy, float* __restrict__ attn, int S)
{
    const int b = blockIdx.x;
    const int t = threadIdx.x;
    __shared__ float w0[2], w1[2];
    float m = -1e30f;
    for (int s = t; s < S; s += 128) m = fmaxf(m, energy[(size_t)s * B + b]);
    #pragma unroll
    for (int off = 32; off; off >>= 1) m = fmaxf(m, __shfl_xor(m, off));
    if ((t & 63) == 0) w0[t >> 6] = m;
    __syncthreads();
    m = fmaxf(w0[0], w0[1]);
    float sum = 0.f;
    for (int s = t; s < S; s += 128) sum += expf(energy[(size_t)s * B + b] - m);
    #pragma unroll
    for (int off = 32; off; off >>= 1) sum += __shfl_xor(sum, off);
    if ((t & 63) == 0) w1[t >> 6] = sum;
    __syncthreads();
    const float inv = 1.f / (w1[0] + w1[1]);
    for (int s = t; s < S; s += 128)
        attn[(size_t)s * B + b] = expf(energy[(size_t)s * B + b] - m) * inv;
}

// =====================================================================
// context partials over s-chunks: part[p][b][h] = sum_{s in chunk} attn*enc
// =====================================================================
static constexpr int CSP = 8;
__global__ __launch_bounds__(512) void context_part(
    const float* __restrict__ attn, const float* __restrict__ enc,
    float* __restrict__ part, int S, int chunk)
{
    const int b = blockIdx.x;
    const int p = blockIdx.y;
    const int h = threadIdx.x;
    const int s0 = p * chunk;
    int s1 = s0 + chunk; if (s1 > S) s1 = S;
    __shared__ float a_s[128];
    if (h < s1 - s0) a_s[h] = attn[(size_t)(s0 + h) * B + b];
    __syncthreads();
    float c = 0.f;
    const float* e = enc + ((size_t)s0 * B + b) * H + h;
    for (int s = s0; s < s1; ++s, e += (size_t)B * H)
        c += a_s[s - s0] * (*e);
    part[((size_t)p * B + b) * H + h] = c;
}

__global__ __launch_bounds__(512) void context_reduce(
    const float* __restrict__ part, float* __restrict__ combined)
{
    const int b = blockIdx.x;
    const int h = threadIdx.x;
    float c = 0.f;
    #pragma unroll
    for (int p = 0; p < CSP; ++p) c += part[((size_t)p * B + b) * H + h];
    combined[(size_t)b * 2 * H + H + h] = c;
}

// =====================================================================
// log_softmax, 3-stage for parallelism
// =====================================================================
static constexpr int LSP = 16;
__global__ __launch_bounds__(256) void lsm_part(
    const float* __restrict__ logits, float* __restrict__ pm,
    float* __restrict__ ps, int V)
{
    const int b = blockIdx.x;
    const int p = blockIdx.y;
    const int t = threadIdx.x;
    const int V4 = V >> 2;
    const int chunk = (V4 + LSP - 1) / LSP;
    const int i0 = p * chunk;
    int i1 = i0 + chunk; if (i1 > V4) i1 = V4;
    const float4* row = (const float4*)(logits + (size_t)b * V);
    __shared__ float sm[4], ss[4];

    float m = -1e30f;
    for (int i = i0 + t; i < i1; i += 256) {
        const float4 v = row[i];
        m = fmaxf(fmaxf(fmaxf(m, v.x), v.y), fmaxf(v.z, v.w));
    }
    #pragma unroll
    for (int off = 32; off; off >>= 1) m = fmaxf(m, __shfl_xor(m, off));
    if ((t & 63) == 0) sm[t >> 6] = m;
    __syncthreads();
    m = fmaxf(fmaxf(sm[0], sm[1]), fmaxf(sm[2], sm[3]));

    float s = 0.f;
    for (int i = i0 + t; i < i1; i += 256) {
        const float4 v = row[i];
        s += expf(v.x - m) + expf(v.y - m) + expf(v.z - m) + expf(v.w - m);
    }
    #pragma unroll
    for (int off = 32; off; off >>= 1) s += __shfl_xor(s, off);
    if ((t & 63) == 0) ss[t >> 6] = s;
    __syncthreads();
    if (t == 0) {
        pm[b * LSP + p] = m;
        ps[b * LSP + p] = ss[0] + ss[1] + ss[2] + ss[3];
    }
}

__global__ __launch_bounds__(64) void lsm_combine(
    const float* __restrict__ pm, const float* __restrict__ ps,
    float* __restrict__ c)
{
    const int b = blockIdx.x;
    const int l = threadIdx.x;
    float m = (l < LSP) ? pm[b * LSP + l] : -1e30f;
    float mm = m;
    #pragma unroll
    for (int off = 32; off; off >>= 1) mm = fmaxf(mm, __shfl_xor(mm, off));
    float s = (l < LSP) ? ps[b * LSP + l] * expf(m - mm) : 0.f;
    #pragma unroll
    for (int off = 32; off; off >>= 1) s += __shfl_xor(s, off);
    if (l == 0) c[b] = mm + logf(s);
}

__global__ __launch_bounds__(256) void lsm_apply(
    float* __restrict__ logits, const float* __restrict__ c, int V)
{
    const int b = blockIdx.y;
    const int i = blockIdx.x * 256 + threadIdx.x;
    const int V4 = V >> 2;
    if (i >= V4) return;
    float4* row = (float4*)(logits + (size_t)b * V);
    float4 v = row[i];
    const float cb = c[b];
    v.x -= cb; v.y -= cb; v.z -= cb; v.w -= cb;
    row[i] = v;
}

// =====================================================================
extern "C" void kernel_launch(void* const* d_in, const int* in_sizes, int n_in,
                              void* d_out, int out_size, void* d_ws, size_t ws_size,
                              hipStream_t stream)
{
    const float* embedded = (const float*)d_in[0];
    const float* hidden   = (const float*)d_in[1];
    const float* enc      = (const float*)d_in[2];
    const float* w_ih     = (const float*)d_in[3];
    const float* w_hh     = (const float*)d_in[4];
    const float* b_ih     = (const float*)d_in[5];
    const float* b_hh     = (const float*)d_in[6];
    const float* bilin_w  = (const float*)d_in[7];
    const float* bilin_b  = (const float*)d_in[8];
    const float* out_w    = (const float*)d_in[9];
    const float* out_b    = (const float*)d_in[10];
    float* out = (float*)d_out;

    const int E = in_sizes[0] / B;            // 512
    const int S = in_sizes[2] / (B * H);      // 400
    const int V = in_sizes[9] / (2 * H);      // 50000

    float* logp = out;
    float* hnew = out + (size_t)B * V;
    float* attn = hnew + (size_t)B * H;

    float* ws       = (float*)d_ws;
    float* gi       = ws;                       // B*3H
    float* gh       = gi + (size_t)B * 3 * H;   // B*3H
    float* tmp      = gh + (size_t)B * 3 * H;   // B*H
    float* energy   = tmp + (size_t)B * H;      // S*B
    float* combined = energy + (size_t)S * B;   // B*2H
    float* part     = combined + (size_t)B * 2 * H; // CSP*B*H
    float* pm       = part + (size_t)CSP * B * H;   // B*LSP
    float* ps       = pm + (size_t)B * LSP;         // B*LSP
    float* cb       = ps + (size_t)B * LSP;         // B

    // 1) gi / gh (bf16 MFMA)
    gemm_mfma_nt<<<(3 * H) / 64, 256, 0, stream>>>(embedded, w_ih, b_ih, gi, E, 3 * H, 3 * H);
    gemm_mfma_nt<<<(3 * H) / 64, 256, 0, stream>>>(hidden, w_hh, b_hh, gh, H, 3 * H, 3 * H);

    // 2) GRU gates
    gru_gates<<<B, H, 0, stream>>>(gi, gh, hidden, hnew, combined);

    // 3) tmp = h_new @ bilin_w[0]  (fp32, tiny)
    gemm_a64_kn<<<H / 64, 256, 0, stream>>>(hnew, bilin_w, tmp, H, H, H);

    // 4) energy
    energy_k<<<(S * B + 3) / 4, 256, 0, stream>>>(tmp, enc, bilin_b, energy, S);

    // 5) attn
    softmax_s<<<B, 128, 0, stream>>>(energy, attn, S);

    // 6) context (partials + reduce)
    const int chunk = (S + CSP - 1) / CSP;
    context_part<<<dim3(B, CSP), 512, 0, stream>>>(attn, enc, part, S, chunk);
    context_reduce<<<B, 512, 0, stream>>>(part, combined);

    // 7) logits (bf16 MFMA)
    gemm_mfma_nt<<<(V + 63) / 64, 256, 0, stream>>>(combined, out_w, out_b, logp, 2 * H, V, V);

    // 8) log_softmax
    lsm_part<<<dim3(B, LSP), 256, 0, stream>>>(logp, pm, ps, V);
    lsm_combine<<<B, 64, 0, stream>>>(pm, ps, cb);
    lsm_apply<<<dim3((V / 4 + 255) / 256, B), 256, 0, stream>>>(logp, cb, V);
}